// Round 6
// baseline (343.437 us; speedup 1.0000x reference)
//
#include <hip/hip_runtime.h>
#include <hip/hip_fp16.h>

#define NN 50000
#define NE 800000

typedef _Float16 half4v __attribute__((ext_vector_type(4)));
typedef _Float16 half8v __attribute__((ext_vector_type(8)));
typedef float f32x4 __attribute__((ext_vector_type(4)));

static __device__ __forceinline__ float lrelu(float x) { return x > 0.f ? x : 0.2f * x; }

// ---------------- edge-index dtype detection (int32 vs int64) ----------------
__global__ void detect_i64_kernel(const unsigned* __restrict__ ei, int* __restrict__ flag) {
  if (threadIdx.x == 0 && blockIdx.x == 0) {
    int is64 = 1;
    for (int i = 0; i < 64; ++i)
      if (ei[2 * i + 1] != 0u) { is64 = 0; break; }
    *flag = is64;
  }
}

static __device__ __forceinline__ int edge_at(const void* ei, int is64, long long idx) {
  if (is64) return (int)((const long long*)ei)[idx];
  return ((const int*)ei)[idx];
}

// ---------------- CSR build ----------------
__global__ void count_kernel(const void* __restrict__ ei, const int* __restrict__ flag,
                             int* __restrict__ counts) {
  int e = blockIdx.x * blockDim.x + threadIdx.x;
  if (e >= NE) return;
  int is64 = *flag;
  int d = edge_at(ei, is64, (long long)NE + e);
  atomicAdd(&counts[d], 1);
}

__global__ void scan_kernel(const int* __restrict__ counts, int* __restrict__ rs) {
  __shared__ int wsum[16];
  __shared__ int carry;
  const int tid = threadIdx.x;
  const int lane = tid & 63, wv = tid >> 6;
  if (tid == 0) { carry = 0; rs[0] = 0; }
  __syncthreads();
  for (int base = 0; base < NN; base += 1024) {
    int i = base + tid;
    int v = (i < NN) ? counts[i] : 0;
    #pragma unroll
    for (int off = 1; off < 64; off <<= 1) {
      int t = __shfl_up(v, off);
      if (lane >= off) v += t;
    }
    if (lane == 63) wsum[wv] = v;
    __syncthreads();
    if (tid == 0) {
      int run = 0;
      #pragma unroll
      for (int j = 0; j < 16; ++j) { run += wsum[j]; wsum[j] = run; }
    }
    __syncthreads();
    int add = carry + (wv ? wsum[wv - 1] : 0);
    if (i < NN) rs[i + 1] = add + v;
    __syncthreads();
    if (tid == 0) carry += wsum[15];
    __syncthreads();
  }
}

__global__ void scatter_kernel(const void* __restrict__ ei, const int* __restrict__ flag,
                               const int* __restrict__ rs, int* __restrict__ cursor,
                               int* __restrict__ ssrc, int* __restrict__ sdst) {
  int e = blockIdx.x * blockDim.x + threadIdx.x;
  if (e >= NE) return;
  int is64 = *flag;
  int s = edge_at(ei, is64, e);
  int d = edge_at(ei, is64, (long long)NE + e);
  int p = atomicAdd(&cursor[d], 1);
  int pos = rs[d] + p;
  ssrc[pos] = s;
  sdst[pos] = d;
}

// ---------------- weight transpose + fp16 convert: Wt[n][k] = W[k][n], K=256 --
__global__ void convert_wt_kernel(const float* __restrict__ W, _Float16* __restrict__ Wt,
                                  int N, int total) {
  int i = blockIdx.x * blockDim.x + threadIdx.x;
  if (i >= total) return;
  int n = i >> 8, k = i & 255;
  Wt[i] = (_Float16)W[(size_t)k * N + n];
}

// ---------------- MFMA fp16 GEMM: C[M,BN] = A[M,256] @ Wt^T ------------------
template<int BN, int NCF, bool A_HALF>
__global__ __launch_bounds__(256) void gemm_mfma(const void* __restrict__ Araw,
                                                 const _Float16* __restrict__ Wt,
                                                 __half* __restrict__ C, int M) {
  __shared__ _Float16 As[64][256 + 8];
  const int tid = threadIdx.x;
  const int bm0 = blockIdx.x * 64;
  if (A_HALF) {
    const _Float16* A = (const _Float16*)Araw;
    for (int idx = tid; idx < 64 * 32; idx += 256) {
      int r = idx >> 5, c8 = (idx & 31) << 3;
      int gr = bm0 + r;
      half8v v = {};
      if (gr < M) v = *(const half8v*)&A[(size_t)gr * 256 + c8];
      *(half8v*)&As[r][c8] = v;
    }
  } else {
    const float* A = (const float*)Araw;
    for (int idx = tid; idx < 64 * 64; idx += 256) {
      int r = idx >> 6, c4 = (idx & 63) << 2;
      int gr = bm0 + r;
      float4 v = make_float4(0.f, 0.f, 0.f, 0.f);
      if (gr < M) v = *(const float4*)&A[(size_t)gr * 256 + c4];
      half4v h = { (_Float16)v.x, (_Float16)v.y, (_Float16)v.z, (_Float16)v.w };
      *(half4v*)&As[r][c4] = h;
    }
  }
  __syncthreads();
  const int lane = tid & 63, wv = tid >> 6;
  const int ncol0 = wv * (16 * NCF);
  const int lrow = lane & 15, lk8 = (lane >> 4) << 3;
  f32x4 acc[4][NCF];
  #pragma unroll
  for (int rf = 0; rf < 4; ++rf)
    #pragma unroll
    for (int cf = 0; cf < NCF; ++cf) acc[rf][cf] = (f32x4){0.f, 0.f, 0.f, 0.f};
  #pragma unroll
  for (int k0 = 0; k0 < 256; k0 += 32) {
    const int ks = k0 + lk8;
    half8v af[4];
    #pragma unroll
    for (int rf = 0; rf < 4; ++rf)
      af[rf] = *(const half8v*)&As[16 * rf + lrow][ks];
    #pragma unroll
    for (int cf = 0; cf < NCF; ++cf) {
      half8v bf = *(const half8v*)&Wt[(size_t)(ncol0 + 16 * cf + lrow) * 256 + ks];
      #pragma unroll
      for (int rf = 0; rf < 4; ++rf)
        acc[rf][cf] = __builtin_amdgcn_mfma_f32_16x16x32_f16(af[rf], bf, acc[rf][cf], 0, 0, 0);
    }
  }
  #pragma unroll
  for (int rf = 0; rf < 4; ++rf) {
    #pragma unroll
    for (int j = 0; j < 4; ++j) {
      int row = bm0 + 16 * rf + 4 * (lane >> 4) + j;
      if (row < M) {
        #pragma unroll
        for (int cf = 0; cf < NCF; ++cf) {
          int col = ncol0 + 16 * cf + lrow;
          C[(size_t)row * BN + col] = __float2half(acc[rf][cf][j]);
        }
      }
    }
  }
}

// ---------------- per-(node,head) attention coefficients (fp16 h) ----------
template<int C>
__global__ void alpha_kernel(const __half* __restrict__ h, const float* __restrict__ aws,
                             const float* __restrict__ awd, float* __restrict__ os,
                             float* __restrict__ od) {
  int i = blockIdx.x * blockDim.x + threadIdx.x;
  if (i >= NN * 8) return;
  int node = i >> 3, head = i & 7;
  const __half2* hp = (const __half2*)(h + (size_t)node * (8 * C) + head * C);
  const float* pws = aws + head * C;
  const float* pwd = awd + head * C;
  float s = 0.f, d = 0.f;
  #pragma unroll
  for (int c = 0; c < C / 2; ++c) {
    float2 v = __half22float2(hp[c]);
    s += v.x * pws[2 * c] + v.y * pws[2 * c + 1];
    d += v.x * pwd[2 * c] + v.y * pwd[2 * c + 1];
  }
  os[i] = s; od[i] = d;
}

// ---------------- per-(edge,head) numerator p = exp(lrelu(as+ad)), fp16 ----
__global__ void pkern(const int* __restrict__ ssrc, const int* __restrict__ sdst,
                      const float* __restrict__ as, const float* __restrict__ ad,
                      __half* __restrict__ ph) {
  int i = blockIdx.x * blockDim.x + threadIdx.x;
  if (i >= NE * 8) return;
  int pos = i >> 3, hd = i & 7;
  int s = ssrc[pos], d = sdst[pos];
  float e = as[s * 8 + hd] + ad[d * 8 + hd];
  ph[i] = __float2half(__expf(lrelu(e)));
}

// ---------------- layer-1 aggregation: pure gather-FMA, 8-deep pipeline ----
// one wave per node; p precomputed (off the critical path); fp16 accumulate.
__global__ __launch_bounds__(256) void agg1_kernel(const __half* __restrict__ h,
    const float* __restrict__ as, const float* __restrict__ ad,
    const int* __restrict__ rs, const int* __restrict__ ssrc,
    const __half* __restrict__ ph,
    const float* __restrict__ bias, __half* __restrict__ out) {
  const int wid = (blockIdx.x * blockDim.x + threadIdx.x) >> 6;
  const int lane = threadIdx.x & 63;
  if (wid >= NN) return;
  const int node = wid;
  const int beg = rs[node], end = rs[node + 1];
  const int hd = lane >> 3;
  float denom;
  __half2 acc01, acc23;
  {
    float p = __expf(lrelu(as[node * 8 + hd] + ad[node * 8 + hd]));   // self loop
    union { float2 f; __half2 q[2]; } u;
    u.f = *(const float2*)&h[(size_t)node * 256 + lane * 4];
    __half2 p2 = __float2half2_rn(p);
    acc01 = __hmul2(p2, u.q[0]);
    acc23 = __hmul2(p2, u.q[1]);
    denom = p;
  }
  int it = beg;
  for (; it + 8 <= end; it += 8) {
    int s[8];
    #pragma unroll
    for (int j = 0; j < 8; ++j) s[j] = ssrc[it + j];
    __half pv[8];
    #pragma unroll
    for (int j = 0; j < 8; ++j) pv[j] = ph[(it + j) * 8 + hd];
    union { float2 f; __half2 q[2]; } u[8];
    #pragma unroll
    for (int j = 0; j < 8; ++j)
      u[j].f = *(const float2*)&h[(size_t)s[j] * 256 + lane * 4];
    #pragma unroll
    for (int j = 0; j < 8; ++j) {
      __half2 p2 = __half2half2(pv[j]);
      acc01 = __hfma2(p2, u[j].q[0], acc01);
      acc23 = __hfma2(p2, u[j].q[1], acc23);
      denom += __half2float(pv[j]);
    }
  }
  for (; it < end; ++it) {
    int s = ssrc[it];
    __half p = ph[it * 8 + hd];
    union { float2 f; __half2 q[2]; } u;
    u.f = *(const float2*)&h[(size_t)s * 256 + lane * 4];
    __half2 p2 = __half2half2(p);
    acc01 = __hfma2(p2, u.q[0], acc01);
    acc23 = __hfma2(p2, u.q[1], acc23);
    denom += __half2float(p);
  }
  const float inv = 1.f / (denom + 1e-16f);
  float2 a01 = __half22float2(acc01);
  float2 a23 = __half22float2(acc23);
  const float4 bv = *(const float4*)&bias[lane * 4];
  float4 o;
  o.x = a01.x * inv + bv.x; o.y = a01.y * inv + bv.y;
  o.z = a23.x * inv + bv.z; o.w = a23.y * inv + bv.w;
  o.x = o.x > 0.f ? o.x : __expf(o.x) - 1.f;
  o.y = o.y > 0.f ? o.y : __expf(o.y) - 1.f;
  o.z = o.z > 0.f ? o.z : __expf(o.z) - 1.f;
  o.w = o.w > 0.f ? o.w : __expf(o.w) - 1.f;
  union { __half2 h2[2]; float2 f2; } w;
  w.h2[0] = __floats2half2_rn(o.x, o.y);
  w.h2[1] = __floats2half2_rn(o.z, o.w);
  *(float2*)&out[(size_t)node * 256 + lane * 4] = w.f2;
}

// ---------------- layer-2 aggregation + bias + log_softmax ------------------
__global__ __launch_bounds__(256) void agg2_kernel(const __half* __restrict__ h,
    const float* __restrict__ as, const float* __restrict__ ad,
    const int* __restrict__ rs, const int* __restrict__ ssrc,
    const __half* __restrict__ ph,
    const float* __restrict__ bias, float* __restrict__ out) {
  const int wid = (blockIdx.x * blockDim.x + threadIdx.x) >> 6;
  const int lane = threadIdx.x & 63;
  if (wid >= NN) return;
  const int node = wid;
  const int beg = rs[node], end = rs[node + 1];
  const int hd = lane >> 3;
  float denom;
  __half2 acc;
  {
    float p = __expf(lrelu(as[node * 8 + hd] + ad[node * 8 + hd]));   // self loop
    __half2 q = ((const __half2*)&h[(size_t)node * 128])[lane];
    acc = __hmul2(__float2half2_rn(p), q);
    denom = p;
  }
  int it = beg;
  for (; it + 8 <= end; it += 8) {
    int s[8];
    #pragma unroll
    for (int j = 0; j < 8; ++j) s[j] = ssrc[it + j];
    __half pv[8];
    #pragma unroll
    for (int j = 0; j < 8; ++j) pv[j] = ph[(it + j) * 8 + hd];
    __half2 q[8];
    #pragma unroll
    for (int j = 0; j < 8; ++j)
      q[j] = ((const __half2*)&h[(size_t)s[j] * 128])[lane];
    #pragma unroll
    for (int j = 0; j < 8; ++j) {
      acc = __hfma2(__half2half2(pv[j]), q[j], acc);
      denom += __half2float(pv[j]);
    }
  }
  for (; it < end; ++it) {
    int s = ssrc[it];
    __half p = ph[it * 8 + hd];
    __half2 q = ((const __half2*)&h[(size_t)s * 128])[lane];
    acc = __hfma2(__half2half2(p), q, acc);
    denom += __half2float(p);
  }
  const float inv = 1.f / (denom + 1e-16f);
  float2 av = __half22float2(acc);
  float v0 = av.x * inv + bias[lane * 2 + 0];
  float v1 = av.y * inv + bias[lane * 2 + 1];
  float mx = fmaxf(v0, v1);
  #pragma unroll
  for (int off = 1; off < 64; off <<= 1) mx = fmaxf(mx, __shfl_xor(mx, off));
  float sum = __expf(v0 - mx) + __expf(v1 - mx);
  #pragma unroll
  for (int off = 1; off < 64; off <<= 1) sum += __shfl_xor(sum, off);
  float lse = mx + __logf(sum);
  float2 o = make_float2(v0 - lse, v1 - lse);
  __builtin_nontemporal_store(o.x, &out[(size_t)node * 128 + lane * 2]);
  __builtin_nontemporal_store(o.y, &out[(size_t)node * 128 + lane * 2 + 1]);
}

// ---------------- host ----------------
extern "C" void kernel_launch(void* const* d_in, const int* in_sizes, int n_in,
                              void* d_out, int out_size, void* d_ws, size_t ws_size,
                              hipStream_t stream) {
  const float* x    = (const float*)d_in[0];
  const void*  ei   = d_in[1];
  const float* W1   = (const float*)d_in[2];
  const float* aS1  = (const float*)d_in[3];
  const float* aD1  = (const float*)d_in[4];
  const float* b1   = (const float*)d_in[5];
  const float* W2   = (const float*)d_in[6];
  const float* aS2  = (const float*)d_in[7];
  const float* aD2  = (const float*)d_in[8];
  const float* b2   = (const float*)d_in[9];
  float* out = (float*)d_out;

  char* ws = (char*)d_ws;
  __half* hh   = (__half*)ws;          ws += (size_t)NN * 256 * 2;  // h (layer1) / h2 (layer2)
  __half* hmid = (__half*)ws;          ws += (size_t)NN * 256 * 2;  // ELU(agg1) fp16
  _Float16* W1t = (_Float16*)ws;       ws += (size_t)256 * 256 * 2; // [N=256][K=256]
  _Float16* W2t = (_Float16*)ws;       ws += (size_t)128 * 256 * 2; // [N=128][K=256]
  float* alS  = (float*)ws;            ws += (size_t)NN * 8 * 4;
  float* alD  = (float*)ws;            ws += (size_t)NN * 8 * 4;
  __half* ph1 = (__half*)ws;           ws += (size_t)NE * 8 * 2;    // per-edge p, layer 1
  __half* ph2 = (__half*)ws;           ws += (size_t)NE * 8 * 2;    // per-edge p, layer 2
  int* counts = (int*)ws;              ws += (size_t)NN * 4;
  int* rs     = (int*)ws;              ws += (size_t)(NN + 1) * 4;
  int* ssrc   = (int*)ws;              ws += (size_t)NE * 4;
  int* sdst   = (int*)ws;              ws += (size_t)NE * 4;
  int* flag   = (int*)ws;              ws += 256;

  // ---- CSR build ----
  detect_i64_kernel<<<1, 64, 0, stream>>>((const unsigned*)ei, flag);
  hipMemsetAsync(counts, 0, (size_t)NN * 4, stream);
  count_kernel<<<(NE + 255) / 256, 256, 0, stream>>>(ei, flag, counts);
  scan_kernel<<<1, 1024, 0, stream>>>(counts, rs);
  hipMemsetAsync(counts, 0, (size_t)NN * 4, stream);
  scatter_kernel<<<(NE + 255) / 256, 256, 0, stream>>>(ei, flag, rs, counts, ssrc, sdst);

  // ---- weight prep ----
  convert_wt_kernel<<<(256 * 256 + 255) / 256, 256, 0, stream>>>(W1, W1t, 256, 256 * 256);
  convert_wt_kernel<<<(128 * 256 + 255) / 256, 256, 0, stream>>>(W2, W2t, 128, 128 * 256);

  const int ngrid = (NN + 63) / 64;  // 782
  // ---- layer 1 ----
  gemm_mfma<256, 4, false><<<ngrid, 256, 0, stream>>>(x, W1t, hh, NN);
  alpha_kernel<32><<<(NN * 8 + 255) / 256, 256, 0, stream>>>(hh, aS1, aD1, alS, alD);
  pkern<<<(NE * 8 + 255) / 256, 256, 0, stream>>>(ssrc, sdst, alS, alD, ph1);
  agg1_kernel<<<(NN + 3) / 4, 256, 0, stream>>>(hh, alS, alD, rs, ssrc, ph1, b1, hmid);

  // ---- layer 2 ----
  gemm_mfma<128, 2, true><<<ngrid, 256, 0, stream>>>(hmid, W2t, hh, NN);
  alpha_kernel<16><<<(NN * 8 + 255) / 256, 256, 0, stream>>>(hh, aS2, aD2, alS, alD);
  pkern<<<(NE * 8 + 255) / 256, 256, 0, stream>>>(ssrc, sdst, alS, alD, ph2);
  agg2_kernel<<<(NN + 3) / 4, 256, 0, stream>>>(hh, alS, alD, rs, ssrc, ph2, b2, out);
}

// Round 7
// 290.394 us; speedup vs baseline: 1.1827x; 1.1827x over previous
//
#include <hip/hip_runtime.h>
#include <hip/hip_fp16.h>

#define NN 50000
#define NE 800000

typedef _Float16 half4v __attribute__((ext_vector_type(4)));
typedef _Float16 half8v __attribute__((ext_vector_type(8)));
typedef float f32x4 __attribute__((ext_vector_type(4)));

static __device__ __forceinline__ float lrelu(float x) { return x > 0.f ? x : 0.2f * x; }

// ---------------- edge-index dtype detection (int32 vs int64) ----------------
__global__ void detect_i64_kernel(const unsigned* __restrict__ ei, int* __restrict__ flag) {
  if (threadIdx.x == 0 && blockIdx.x == 0) {
    int is64 = 1;
    for (int i = 0; i < 64; ++i)
      if (ei[2 * i + 1] != 0u) { is64 = 0; break; }
    *flag = is64;
  }
}

static __device__ __forceinline__ int edge_at(const void* ei, int is64, long long idx) {
  if (is64) return (int)((const long long*)ei)[idx];
  return ((const int*)ei)[idx];
}

// ---------------- CSR build ----------------
__global__ void count_kernel(const void* __restrict__ ei, const int* __restrict__ flag,
                             int* __restrict__ counts) {
  int e = blockIdx.x * blockDim.x + threadIdx.x;
  if (e >= NE) return;
  int is64 = *flag;
  int d = edge_at(ei, is64, (long long)NE + e);
  atomicAdd(&counts[d], 1);
}

// two-level scan: 196 blocks x 256
static __device__ __forceinline__ int block_scan_inc(int v, int tid) {
  __shared__ int ws[4];
  const int lane = tid & 63, wv = tid >> 6;
  #pragma unroll
  for (int off = 1; off < 64; off <<= 1) {
    int t = __shfl_up(v, off);
    if (lane >= off) v += t;
  }
  if (lane == 63) ws[wv] = v;
  __syncthreads();
  int add = 0;
  #pragma unroll
  for (int j = 0; j < 4; ++j) if (j < wv) add += ws[j];
  return v + add;
}

__global__ void scan1_kernel(const int* __restrict__ counts, int* __restrict__ bsums) {
  __shared__ int ws[4];
  const int tid = threadIdx.x;
  const int lane = tid & 63, wv = tid >> 6;
  int i = blockIdx.x * 256 + tid;
  int v = (i < NN) ? counts[i] : 0;
  #pragma unroll
  for (int off = 1; off < 64; off <<= 1) v += __shfl_xor(v, off);
  if (lane == 0) ws[wv] = v;
  __syncthreads();
  if (tid == 0) bsums[blockIdx.x] = ws[0] + ws[1] + ws[2] + ws[3];
}

__global__ void scan2_kernel(int* __restrict__ bsums, int nb) {
  const int tid = threadIdx.x;
  int v = (tid < nb) ? bsums[tid] : 0;
  int inc = block_scan_inc(v, tid);
  if (tid < nb) bsums[tid] = inc - v;   // exclusive
}

__global__ void scan3_kernel(const int* __restrict__ counts, const int* __restrict__ bsums,
                             int* __restrict__ rs) {
  const int tid = threadIdx.x;
  int i = blockIdx.x * 256 + tid;
  int v = (i < NN) ? counts[i] : 0;
  int inc = block_scan_inc(v, tid);
  if (i < NN) rs[i + 1] = bsums[blockIdx.x] + inc;
  if (i == 0) rs[0] = 0;
}

__global__ void scatter_kernel(const void* __restrict__ ei, const int* __restrict__ flag,
                               const int* __restrict__ rs, int* __restrict__ cursor,
                               int* __restrict__ ssrc) {
  int e = blockIdx.x * blockDim.x + threadIdx.x;
  if (e >= NE) return;
  int is64 = *flag;
  int s = edge_at(ei, is64, e);
  int d = edge_at(ei, is64, (long long)NE + e);
  int p = atomicAdd(&cursor[d], 1);
  ssrc[rs[d] + p] = s;
}

// ---------------- weight transpose + fp16 convert: Wt[n][k] = W[k][n], K=256 --
__global__ void convert_wt_kernel(const float* __restrict__ W, _Float16* __restrict__ Wt,
                                  int N, int total) {
  int i = blockIdx.x * blockDim.x + threadIdx.x;
  if (i >= total) return;
  int n = i >> 8, k = i & 255;
  Wt[i] = (_Float16)W[(size_t)k * N + n];
}

// ---------------- MFMA fp16 GEMM: C[M,BN] = A[M,256] @ Wt^T ------------------
template<int BN, int NCF, bool A_HALF>
__global__ __launch_bounds__(256) void gemm_mfma(const void* __restrict__ Araw,
                                                 const _Float16* __restrict__ Wt,
                                                 __half* __restrict__ C, int M) {
  __shared__ _Float16 As[64][256 + 8];
  const int tid = threadIdx.x;
  const int bm0 = blockIdx.x * 64;
  if (A_HALF) {
    const _Float16* A = (const _Float16*)Araw;
    for (int idx = tid; idx < 64 * 32; idx += 256) {
      int r = idx >> 5, c8 = (idx & 31) << 3;
      int gr = bm0 + r;
      half8v v = {};
      if (gr < M) v = *(const half8v*)&A[(size_t)gr * 256 + c8];
      *(half8v*)&As[r][c8] = v;
    }
  } else {
    const float* A = (const float*)Araw;
    for (int idx = tid; idx < 64 * 64; idx += 256) {
      int r = idx >> 6, c4 = (idx & 63) << 2;
      int gr = bm0 + r;
      float4 v = make_float4(0.f, 0.f, 0.f, 0.f);
      if (gr < M) v = *(const float4*)&A[(size_t)gr * 256 + c4];
      half4v h = { (_Float16)v.x, (_Float16)v.y, (_Float16)v.z, (_Float16)v.w };
      *(half4v*)&As[r][c4] = h;
    }
  }
  __syncthreads();
  const int lane = tid & 63, wv = tid >> 6;
  const int ncol0 = wv * (16 * NCF);
  const int lrow = lane & 15, lk8 = (lane >> 4) << 3;
  f32x4 acc[4][NCF];
  #pragma unroll
  for (int rf = 0; rf < 4; ++rf)
    #pragma unroll
    for (int cf = 0; cf < NCF; ++cf) acc[rf][cf] = (f32x4){0.f, 0.f, 0.f, 0.f};
  #pragma unroll
  for (int k0 = 0; k0 < 256; k0 += 32) {
    const int ks = k0 + lk8;
    half8v af[4];
    #pragma unroll
    for (int rf = 0; rf < 4; ++rf)
      af[rf] = *(const half8v*)&As[16 * rf + lrow][ks];
    #pragma unroll
    for (int cf = 0; cf < NCF; ++cf) {
      half8v bf = *(const half8v*)&Wt[(size_t)(ncol0 + 16 * cf + lrow) * 256 + ks];
      #pragma unroll
      for (int rf = 0; rf < 4; ++rf)
        acc[rf][cf] = __builtin_amdgcn_mfma_f32_16x16x32_f16(af[rf], bf, acc[rf][cf], 0, 0, 0);
    }
  }
  #pragma unroll
  for (int rf = 0; rf < 4; ++rf) {
    #pragma unroll
    for (int j = 0; j < 4; ++j) {
      int row = bm0 + 16 * rf + 4 * (lane >> 4) + j;
      if (row < M) {
        #pragma unroll
        for (int cf = 0; cf < NCF; ++cf) {
          int col = ncol0 + 16 * cf + lrow;
          C[(size_t)row * BN + col] = __float2half(acc[rf][cf][j]);
        }
      }
    }
  }
}

// ---------------- per-(node,head) attention coefficients (fp16 h) ----------
template<int C>
__global__ void alpha_kernel(const __half* __restrict__ h, const float* __restrict__ aws,
                             const float* __restrict__ awd, float* __restrict__ os,
                             float* __restrict__ od) {
  int i = blockIdx.x * blockDim.x + threadIdx.x;
  if (i >= NN * 8) return;
  int node = i >> 3, head = i & 7;
  const __half2* hp = (const __half2*)(h + (size_t)node * (8 * C) + head * C);
  const float* pws = aws + head * C;
  const float* pwd = awd + head * C;
  float s = 0.f, d = 0.f;
  #pragma unroll
  for (int c = 0; c < C / 2; ++c) {
    float2 v = __half22float2(hp[c]);
    s += v.x * pws[2 * c] + v.y * pws[2 * c + 1];
    d += v.x * pwd[2 * c] + v.y * pwd[2 * c + 1];
  }
  os[i] = s; od[i] = d;
}

// ---------------- layer-1 aggregation: dual-stream 4-deep edge loop --------
// one wave per node; in-loop p=exp(lrelu(.)); fp16 accumulate.
__global__ __launch_bounds__(256) void agg1_kernel(const __half* __restrict__ h,
    const float* __restrict__ as, const float* __restrict__ ad,
    const int* __restrict__ rs, const int* __restrict__ ssrc,
    const float* __restrict__ bias, __half* __restrict__ out) {
  const int wid = (blockIdx.x * blockDim.x + threadIdx.x) >> 6;
  const int lane = threadIdx.x & 63;
  if (wid >= NN) return;
  const int node = wid;
  const int beg = rs[node], end = rs[node + 1];
  const int hd = lane >> 3;
  const float advh = ad[node * 8 + hd];
  float denom;
  __half2 acc01, acc23;
  {
    float p = __expf(lrelu(as[node * 8 + hd] + advh));   // self loop
    union { float2 f; __half2 q[2]; } u;
    u.f = *(const float2*)&h[(size_t)node * 256 + lane * 4];
    __half2 p2 = __float2half2_rn(p);
    acc01 = __hmul2(p2, u.q[0]);
    acc23 = __hmul2(p2, u.q[1]);
    denom = p;
  }
  const int mid = beg + ((end - beg) >> 1);
  int itA = beg, itB = mid;
  for (; itA + 4 <= mid && itB + 4 <= end; itA += 4, itB += 4) {
    int sA0 = ssrc[itA], sA1 = ssrc[itA + 1], sA2 = ssrc[itA + 2], sA3 = ssrc[itA + 3];
    int sB0 = ssrc[itB], sB1 = ssrc[itB + 1], sB2 = ssrc[itB + 2], sB3 = ssrc[itB + 3];
    float bA0 = as[sA0 * 8 + hd], bA1 = as[sA1 * 8 + hd],
          bA2 = as[sA2 * 8 + hd], bA3 = as[sA3 * 8 + hd];
    float bB0 = as[sB0 * 8 + hd], bB1 = as[sB1 * 8 + hd],
          bB2 = as[sB2 * 8 + hd], bB3 = as[sB3 * 8 + hd];
    union { float2 f; __half2 q[2]; } uA0, uA1, uA2, uA3, uB0, uB1, uB2, uB3;
    uA0.f = *(const float2*)&h[(size_t)sA0 * 256 + lane * 4];
    uA1.f = *(const float2*)&h[(size_t)sA1 * 256 + lane * 4];
    uA2.f = *(const float2*)&h[(size_t)sA2 * 256 + lane * 4];
    uA3.f = *(const float2*)&h[(size_t)sA3 * 256 + lane * 4];
    uB0.f = *(const float2*)&h[(size_t)sB0 * 256 + lane * 4];
    uB1.f = *(const float2*)&h[(size_t)sB1 * 256 + lane * 4];
    uB2.f = *(const float2*)&h[(size_t)sB2 * 256 + lane * 4];
    uB3.f = *(const float2*)&h[(size_t)sB3 * 256 + lane * 4];
    float pA0 = __expf(lrelu(bA0 + advh)), pA1 = __expf(lrelu(bA1 + advh));
    float pA2 = __expf(lrelu(bA2 + advh)), pA3 = __expf(lrelu(bA3 + advh));
    float pB0 = __expf(lrelu(bB0 + advh)), pB1 = __expf(lrelu(bB1 + advh));
    float pB2 = __expf(lrelu(bB2 + advh)), pB3 = __expf(lrelu(bB3 + advh));
    denom += pA0 + pA1 + pA2 + pA3 + pB0 + pB1 + pB2 + pB3;
    __half2 p2;
    p2 = __float2half2_rn(pA0); acc01 = __hfma2(p2, uA0.q[0], acc01); acc23 = __hfma2(p2, uA0.q[1], acc23);
    p2 = __float2half2_rn(pA1); acc01 = __hfma2(p2, uA1.q[0], acc01); acc23 = __hfma2(p2, uA1.q[1], acc23);
    p2 = __float2half2_rn(pA2); acc01 = __hfma2(p2, uA2.q[0], acc01); acc23 = __hfma2(p2, uA2.q[1], acc23);
    p2 = __float2half2_rn(pA3); acc01 = __hfma2(p2, uA3.q[0], acc01); acc23 = __hfma2(p2, uA3.q[1], acc23);
    p2 = __float2half2_rn(pB0); acc01 = __hfma2(p2, uB0.q[0], acc01); acc23 = __hfma2(p2, uB0.q[1], acc23);
    p2 = __float2half2_rn(pB1); acc01 = __hfma2(p2, uB1.q[0], acc01); acc23 = __hfma2(p2, uB1.q[1], acc23);
    p2 = __float2half2_rn(pB2); acc01 = __hfma2(p2, uB2.q[0], acc01); acc23 = __hfma2(p2, uB2.q[1], acc23);
    p2 = __float2half2_rn(pB3); acc01 = __hfma2(p2, uB3.q[0], acc01); acc23 = __hfma2(p2, uB3.q[1], acc23);
  }
  for (; itA < mid; ++itA) {
    int s = ssrc[itA];
    float p = __expf(lrelu(as[s * 8 + hd] + advh));
    union { float2 f; __half2 q[2]; } u;
    u.f = *(const float2*)&h[(size_t)s * 256 + lane * 4];
    __half2 p2 = __float2half2_rn(p);
    acc01 = __hfma2(p2, u.q[0], acc01);
    acc23 = __hfma2(p2, u.q[1], acc23);
    denom += p;
  }
  for (; itB < end; ++itB) {
    int s = ssrc[itB];
    float p = __expf(lrelu(as[s * 8 + hd] + advh));
    union { float2 f; __half2 q[2]; } u;
    u.f = *(const float2*)&h[(size_t)s * 256 + lane * 4];
    __half2 p2 = __float2half2_rn(p);
    acc01 = __hfma2(p2, u.q[0], acc01);
    acc23 = __hfma2(p2, u.q[1], acc23);
    denom += p;
  }
  const float inv = 1.f / (denom + 1e-16f);
  float2 a01 = __half22float2(acc01);
  float2 a23 = __half22float2(acc23);
  const float4 bv = *(const float4*)&bias[lane * 4];
  float4 o;
  o.x = a01.x * inv + bv.x; o.y = a01.y * inv + bv.y;
  o.z = a23.x * inv + bv.z; o.w = a23.y * inv + bv.w;
  o.x = o.x > 0.f ? o.x : __expf(o.x) - 1.f;
  o.y = o.y > 0.f ? o.y : __expf(o.y) - 1.f;
  o.z = o.z > 0.f ? o.z : __expf(o.z) - 1.f;
  o.w = o.w > 0.f ? o.w : __expf(o.w) - 1.f;
  union { __half2 h2[2]; float2 f2; } w;
  w.h2[0] = __floats2half2_rn(o.x, o.y);
  w.h2[1] = __floats2half2_rn(o.z, o.w);
  *(float2*)&out[(size_t)node * 256 + lane * 4] = w.f2;
}

// ---------------- layer-2 aggregation + bias + log_softmax ------------------
__global__ __launch_bounds__(256) void agg2_kernel(const __half* __restrict__ h,
    const float* __restrict__ as, const float* __restrict__ ad,
    const int* __restrict__ rs, const int* __restrict__ ssrc,
    const float* __restrict__ bias, float* __restrict__ out) {
  const int wid = (blockIdx.x * blockDim.x + threadIdx.x) >> 6;
  const int lane = threadIdx.x & 63;
  if (wid >= NN) return;
  const int node = wid;
  const int beg = rs[node], end = rs[node + 1];
  const int hd = lane >> 3;
  const float advh = ad[node * 8 + hd];
  float denom;
  __half2 acc;
  {
    float p = __expf(lrelu(as[node * 8 + hd] + advh));   // self loop
    __half2 q = ((const __half2*)&h[(size_t)node * 128])[lane];
    acc = __hmul2(__float2half2_rn(p), q);
    denom = p;
  }
  const int mid = beg + ((end - beg) >> 1);
  int itA = beg, itB = mid;
  for (; itA + 4 <= mid && itB + 4 <= end; itA += 4, itB += 4) {
    int sA0 = ssrc[itA], sA1 = ssrc[itA + 1], sA2 = ssrc[itA + 2], sA3 = ssrc[itA + 3];
    int sB0 = ssrc[itB], sB1 = ssrc[itB + 1], sB2 = ssrc[itB + 2], sB3 = ssrc[itB + 3];
    float bA0 = as[sA0 * 8 + hd], bA1 = as[sA1 * 8 + hd],
          bA2 = as[sA2 * 8 + hd], bA3 = as[sA3 * 8 + hd];
    float bB0 = as[sB0 * 8 + hd], bB1 = as[sB1 * 8 + hd],
          bB2 = as[sB2 * 8 + hd], bB3 = as[sB3 * 8 + hd];
    __half2 qA0 = ((const __half2*)&h[(size_t)sA0 * 128])[lane];
    __half2 qA1 = ((const __half2*)&h[(size_t)sA1 * 128])[lane];
    __half2 qA2 = ((const __half2*)&h[(size_t)sA2 * 128])[lane];
    __half2 qA3 = ((const __half2*)&h[(size_t)sA3 * 128])[lane];
    __half2 qB0 = ((const __half2*)&h[(size_t)sB0 * 128])[lane];
    __half2 qB1 = ((const __half2*)&h[(size_t)sB1 * 128])[lane];
    __half2 qB2 = ((const __half2*)&h[(size_t)sB2 * 128])[lane];
    __half2 qB3 = ((const __half2*)&h[(size_t)sB3 * 128])[lane];
    float pA0 = __expf(lrelu(bA0 + advh)), pA1 = __expf(lrelu(bA1 + advh));
    float pA2 = __expf(lrelu(bA2 + advh)), pA3 = __expf(lrelu(bA3 + advh));
    float pB0 = __expf(lrelu(bB0 + advh)), pB1 = __expf(lrelu(bB1 + advh));
    float pB2 = __expf(lrelu(bB2 + advh)), pB3 = __expf(lrelu(bB3 + advh));
    denom += pA0 + pA1 + pA2 + pA3 + pB0 + pB1 + pB2 + pB3;
    acc = __hfma2(__float2half2_rn(pA0), qA0, acc);
    acc = __hfma2(__float2half2_rn(pA1), qA1, acc);
    acc = __hfma2(__float2half2_rn(pA2), qA2, acc);
    acc = __hfma2(__float2half2_rn(pA3), qA3, acc);
    acc = __hfma2(__float2half2_rn(pB0), qB0, acc);
    acc = __hfma2(__float2half2_rn(pB1), qB1, acc);
    acc = __hfma2(__float2half2_rn(pB2), qB2, acc);
    acc = __hfma2(__float2half2_rn(pB3), qB3, acc);
  }
  for (; itA < mid; ++itA) {
    int s = ssrc[itA];
    float p = __expf(lrelu(as[s * 8 + hd] + advh));
    __half2 q = ((const __half2*)&h[(size_t)s * 128])[lane];
    acc = __hfma2(__float2half2_rn(p), q, acc);
    denom += p;
  }
  for (; itB < end; ++itB) {
    int s = ssrc[itB];
    float p = __expf(lrelu(as[s * 8 + hd] + advh));
    __half2 q = ((const __half2*)&h[(size_t)s * 128])[lane];
    acc = __hfma2(__float2half2_rn(p), q, acc);
    denom += p;
  }
  const float inv = 1.f / (denom + 1e-16f);
  float2 av = __half22float2(acc);
  float v0 = av.x * inv + bias[lane * 2 + 0];
  float v1 = av.y * inv + bias[lane * 2 + 1];
  float mx = fmaxf(v0, v1);
  #pragma unroll
  for (int off = 1; off < 64; off <<= 1) mx = fmaxf(mx, __shfl_xor(mx, off));
  float sum = __expf(v0 - mx) + __expf(v1 - mx);
  #pragma unroll
  for (int off = 1; off < 64; off <<= 1) sum += __shfl_xor(sum, off);
  float lse = mx + __logf(sum);
  float2 o = make_float2(v0 - lse, v1 - lse);
  __builtin_nontemporal_store(o.x, &out[(size_t)node * 128 + lane * 2]);
  __builtin_nontemporal_store(o.y, &out[(size_t)node * 128 + lane * 2 + 1]);
}

// ---------------- host ----------------
extern "C" void kernel_launch(void* const* d_in, const int* in_sizes, int n_in,
                              void* d_out, int out_size, void* d_ws, size_t ws_size,
                              hipStream_t stream) {
  const float* x    = (const float*)d_in[0];
  const void*  ei   = d_in[1];
  const float* W1   = (const float*)d_in[2];
  const float* aS1  = (const float*)d_in[3];
  const float* aD1  = (const float*)d_in[4];
  const float* b1   = (const float*)d_in[5];
  const float* W2   = (const float*)d_in[6];
  const float* aS2  = (const float*)d_in[7];
  const float* aD2  = (const float*)d_in[8];
  const float* b2   = (const float*)d_in[9];
  float* out = (float*)d_out;

  char* ws = (char*)d_ws;
  __half* hh   = (__half*)ws;          ws += (size_t)NN * 256 * 2;  // h (layer1) / h2 (layer2)
  __half* hmid = (__half*)ws;          ws += (size_t)NN * 256 * 2;  // ELU(agg1) fp16
  _Float16* W1t = (_Float16*)ws;       ws += (size_t)256 * 256 * 2; // [N=256][K=256]
  _Float16* W2t = (_Float16*)ws;       ws += (size_t)128 * 256 * 2; // [N=128][K=256]
  float* alS  = (float*)ws;            ws += (size_t)NN * 8 * 4;
  float* alD  = (float*)ws;            ws += (size_t)NN * 8 * 4;
  int* counts = (int*)ws;              ws += (size_t)NN * 4;
  int* rs     = (int*)ws;              ws += (size_t)(NN + 1) * 4;
  int* bsums  = (int*)ws;              ws += (size_t)256 * 4;
  int* ssrc   = (int*)ws;              ws += (size_t)NE * 4;
  int* flag   = (int*)ws;              ws += 256;

  const int NB = (NN + 255) / 256;     // 196 scan blocks

  // ---- CSR build ----
  detect_i64_kernel<<<1, 64, 0, stream>>>((const unsigned*)ei, flag);
  hipMemsetAsync(counts, 0, (size_t)NN * 4, stream);
  count_kernel<<<(NE + 255) / 256, 256, 0, stream>>>(ei, flag, counts);
  scan1_kernel<<<NB, 256, 0, stream>>>(counts, bsums);
  scan2_kernel<<<1, 256, 0, stream>>>(bsums, NB);
  scan3_kernel<<<NB, 256, 0, stream>>>(counts, bsums, rs);
  hipMemsetAsync(counts, 0, (size_t)NN * 4, stream);
  scatter_kernel<<<(NE + 255) / 256, 256, 0, stream>>>(ei, flag, rs, counts, ssrc);

  // ---- weight prep ----
  convert_wt_kernel<<<(256 * 256 + 255) / 256, 256, 0, stream>>>(W1, W1t, 256, 256 * 256);
  convert_wt_kernel<<<(128 * 256 + 255) / 256, 256, 0, stream>>>(W2, W2t, 128, 128 * 256);

  const int ngrid = (NN + 63) / 64;  // 782
  // ---- layer 1 ----
  gemm_mfma<256, 4, false><<<ngrid, 256, 0, stream>>>(x, W1t, hh, NN);
  alpha_kernel<32><<<(NN * 8 + 255) / 256, 256, 0, stream>>>(hh, aS1, aD1, alS, alD);
  agg1_kernel<<<(NN + 3) / 4, 256, 0, stream>>>(hh, alS, alD, rs, ssrc, b1, hmid);

  // ---- layer 2 ----
  gemm_mfma<128, 2, true><<<ngrid, 256, 0, stream>>>(hmid, W2t, hh, NN);
  alpha_kernel<16><<<(NN * 8 + 255) / 256, 256, 0, stream>>>(hh, aS2, aD2, alS, alD);
  agg2_kernel<<<(NN + 3) / 4, 256, 0, stream>>>(hh, alS, alD, rs, ssrc, b2, out);
}

// Round 8
// 278.347 us; speedup vs baseline: 1.2338x; 1.0433x over previous
//
#include <hip/hip_runtime.h>
#include <hip/hip_fp16.h>

#define NN 50000
#define NE 800000

typedef _Float16 half4v __attribute__((ext_vector_type(4)));
typedef _Float16 half8v __attribute__((ext_vector_type(8)));
typedef float f32x4 __attribute__((ext_vector_type(4)));

static __device__ __forceinline__ float lrelu(float x) { return x > 0.f ? x : 0.2f * x; }

// ---------------- edge-index dtype detection (int32 vs int64) ----------------
__global__ void detect_i64_kernel(const unsigned* __restrict__ ei, int* __restrict__ flag) {
  if (threadIdx.x == 0 && blockIdx.x == 0) {
    int is64 = 1;
    for (int i = 0; i < 64; ++i)
      if (ei[2 * i + 1] != 0u) { is64 = 0; break; }
    *flag = is64;
  }
}

static __device__ __forceinline__ int edge_at(const void* ei, int is64, long long idx) {
  if (is64) return (int)((const long long*)ei)[idx];
  return ((const int*)ei)[idx];
}

// ---------------- CSR build ----------------
__global__ void count_kernel(const void* __restrict__ ei, const int* __restrict__ flag,
                             int* __restrict__ counts) {
  int e = blockIdx.x * blockDim.x + threadIdx.x;
  if (e >= NE) return;
  int is64 = *flag;
  int d = edge_at(ei, is64, (long long)NE + e);
  atomicAdd(&counts[d], 1);
}

// two-level scan: 196 blocks x 256
static __device__ __forceinline__ int block_scan_inc(int v, int tid) {
  __shared__ int ws[4];
  const int lane = tid & 63, wv = tid >> 6;
  #pragma unroll
  for (int off = 1; off < 64; off <<= 1) {
    int t = __shfl_up(v, off);
    if (lane >= off) v += t;
  }
  if (lane == 63) ws[wv] = v;
  __syncthreads();
  int add = 0;
  #pragma unroll
  for (int j = 0; j < 4; ++j) if (j < wv) add += ws[j];
  return v + add;
}

__global__ void scan1_kernel(const int* __restrict__ counts, int* __restrict__ bsums) {
  __shared__ int ws[4];
  const int tid = threadIdx.x;
  const int lane = tid & 63, wv = tid >> 6;
  int i = blockIdx.x * 256 + tid;
  int v = (i < NN) ? counts[i] : 0;
  #pragma unroll
  for (int off = 1; off < 64; off <<= 1) v += __shfl_xor(v, off);
  if (lane == 0) ws[wv] = v;
  __syncthreads();
  if (tid == 0) bsums[blockIdx.x] = ws[0] + ws[1] + ws[2] + ws[3];
}

__global__ void scan2_kernel(int* __restrict__ bsums, int nb) {
  const int tid = threadIdx.x;
  int v = (tid < nb) ? bsums[tid] : 0;
  int inc = block_scan_inc(v, tid);
  if (tid < nb) bsums[tid] = inc - v;   // exclusive
}

__global__ void scan3_kernel(const int* __restrict__ counts, const int* __restrict__ bsums,
                             int* __restrict__ rs) {
  const int tid = threadIdx.x;
  int i = blockIdx.x * 256 + tid;
  int v = (i < NN) ? counts[i] : 0;
  int inc = block_scan_inc(v, tid);
  if (i < NN) rs[i + 1] = bsums[blockIdx.x] + inc;
  if (i == 0) rs[0] = 0;
}

__global__ void scatter_kernel(const void* __restrict__ ei, const int* __restrict__ flag,
                               const int* __restrict__ rs, int* __restrict__ cursor,
                               int* __restrict__ ssrc) {
  int e = blockIdx.x * blockDim.x + threadIdx.x;
  if (e >= NE) return;
  int is64 = *flag;
  int s = edge_at(ei, is64, e);
  int d = edge_at(ei, is64, (long long)NE + e);
  int p = atomicAdd(&cursor[d], 1);
  ssrc[rs[d] + p] = s;
}

// ---------------- weight transpose + fp16 convert: Wt[n][k] = W[k][n] -------
__global__ void convert_wt_kernel(const float* __restrict__ W, _Float16* __restrict__ Wt,
                                  int N, int total) {
  int i = blockIdx.x * blockDim.x + threadIdx.x;
  if (i >= total) return;
  int n = i >> 8, k = i & 255;
  Wt[i] = (_Float16)W[(size_t)k * N + n];
}

// ---------------- alpha-weight fold: Wa[j][k] = sum_c W[k][head*C+c]*a[head][c]
// j in 0..15: j<8 -> aS head j ; j>=8 -> aD head j-8.  Wa is [16][256] fp16.
__global__ void convert_wa_kernel(const float* __restrict__ W,
                                  const float* __restrict__ aS,
                                  const float* __restrict__ aD,
                                  _Float16* __restrict__ Wa, int N, int C) {
  int i = blockIdx.x * blockDim.x + threadIdx.x;
  if (i >= 16 * 256) return;
  int j = i >> 8, k = i & 255;
  int head = j & 7;
  const float* a = (j < 8) ? aS : aD;
  float s = 0.f;
  for (int c = 0; c < C; ++c)
    s += W[(size_t)k * N + head * C + c] * a[head * C + c];
  Wa[i] = (_Float16)s;
}

// ---------------- MFMA fp16 GEMM + fused alpha columns -----------------------
// C[M,BN] = A[M,256] @ Wt^T ; wave 0 additionally computes A @ Wa^T (16 cols)
// and stores them to alS/alD (fp32).
template<int BN, int NCF, bool A_HALF>
__global__ __launch_bounds__(256) void gemm_mfma(const void* __restrict__ Araw,
                                                 const _Float16* __restrict__ Wt,
                                                 const _Float16* __restrict__ Wa,
                                                 __half* __restrict__ C,
                                                 float* __restrict__ alS,
                                                 float* __restrict__ alD, int M) {
  __shared__ _Float16 As[64][256 + 8];
  const int tid = threadIdx.x;
  const int bm0 = blockIdx.x * 64;
  if (A_HALF) {
    const _Float16* A = (const _Float16*)Araw;
    for (int idx = tid; idx < 64 * 32; idx += 256) {
      int r = idx >> 5, c8 = (idx & 31) << 3;
      int gr = bm0 + r;
      half8v v = {};
      if (gr < M) v = *(const half8v*)&A[(size_t)gr * 256 + c8];
      *(half8v*)&As[r][c8] = v;
    }
  } else {
    const float* A = (const float*)Araw;
    for (int idx = tid; idx < 64 * 64; idx += 256) {
      int r = idx >> 6, c4 = (idx & 63) << 2;
      int gr = bm0 + r;
      float4 v = make_float4(0.f, 0.f, 0.f, 0.f);
      if (gr < M) v = *(const float4*)&A[(size_t)gr * 256 + c4];
      half4v h = { (_Float16)v.x, (_Float16)v.y, (_Float16)v.z, (_Float16)v.w };
      *(half4v*)&As[r][c4] = h;
    }
  }
  __syncthreads();
  const int lane = tid & 63, wv = tid >> 6;
  const int ncol0 = wv * (16 * NCF);
  const int lrow = lane & 15, lk8 = (lane >> 4) << 3;
  f32x4 acc[4][NCF];
  f32x4 acca[4];
  #pragma unroll
  for (int rf = 0; rf < 4; ++rf) {
    acca[rf] = (f32x4){0.f, 0.f, 0.f, 0.f};
    #pragma unroll
    for (int cf = 0; cf < NCF; ++cf) acc[rf][cf] = (f32x4){0.f, 0.f, 0.f, 0.f};
  }
  #pragma unroll
  for (int k0 = 0; k0 < 256; k0 += 32) {
    const int ks = k0 + lk8;
    half8v af[4];
    #pragma unroll
    for (int rf = 0; rf < 4; ++rf)
      af[rf] = *(const half8v*)&As[16 * rf + lrow][ks];
    #pragma unroll
    for (int cf = 0; cf < NCF; ++cf) {
      half8v bf = *(const half8v*)&Wt[(size_t)(ncol0 + 16 * cf + lrow) * 256 + ks];
      #pragma unroll
      for (int rf = 0; rf < 4; ++rf)
        acc[rf][cf] = __builtin_amdgcn_mfma_f32_16x16x32_f16(af[rf], bf, acc[rf][cf], 0, 0, 0);
    }
    if (wv == 0) {
      half8v bfa = *(const half8v*)&Wa[(size_t)lrow * 256 + ks];
      #pragma unroll
      for (int rf = 0; rf < 4; ++rf)
        acca[rf] = __builtin_amdgcn_mfma_f32_16x16x32_f16(af[rf], bfa, acca[rf], 0, 0, 0);
    }
  }
  #pragma unroll
  for (int rf = 0; rf < 4; ++rf) {
    #pragma unroll
    for (int j = 0; j < 4; ++j) {
      int row = bm0 + 16 * rf + 4 * (lane >> 4) + j;
      if (row < M) {
        #pragma unroll
        for (int cf = 0; cf < NCF; ++cf) {
          int col = ncol0 + 16 * cf + lrow;
          C[(size_t)row * BN + col] = __float2half(acc[rf][cf][j]);
        }
      }
    }
  }
  if (wv == 0) {
    #pragma unroll
    for (int rf = 0; rf < 4; ++rf) {
      #pragma unroll
      for (int j = 0; j < 4; ++j) {
        int row = bm0 + 16 * rf + 4 * (lane >> 4) + j;
        if (row < M) {
          float v = acca[rf][j];
          if (lrow < 8) alS[row * 8 + lrow] = v;
          else          alD[row * 8 + (lrow - 8)] = v;
        }
      }
    }
  }
}

// ---------------- layer-1 aggregation: scalar-addressed gather-FMA ----------
// one wave per node; s via readfirstlane -> SGPR base addressing; fp16 acc.
__global__ __launch_bounds__(256) void agg1_kernel(const __half* __restrict__ h,
    const float* __restrict__ as, const float* __restrict__ ad,
    const int* __restrict__ rs, const int* __restrict__ ssrc,
    const float* __restrict__ bias, __half* __restrict__ out) {
  const int wid = (blockIdx.x * blockDim.x + threadIdx.x) >> 6;
  const int lane = threadIdx.x & 63;
  if (wid >= NN) return;
  const int node = wid;
  const int beg = rs[node], end = rs[node + 1];
  const int hd = lane >> 3;
  const float advh = ad[node * 8 + hd];
  float denom;
  __half2 acc01, acc23;
  {
    float p = __expf(lrelu(as[node * 8 + hd] + advh));   // self loop
    union { float2 f; __half2 q[2]; } u;
    u.f = *(const float2*)&h[(size_t)node * 256 + lane * 4];
    __half2 p2 = __float2half2_rn(p);
    acc01 = __hmul2(p2, u.q[0]);
    acc23 = __hmul2(p2, u.q[1]);
    denom = p;
  }
  int it = beg;
  for (; it + 8 <= end; it += 8) {
    int s0 = __builtin_amdgcn_readfirstlane(ssrc[it + 0]);
    int s1 = __builtin_amdgcn_readfirstlane(ssrc[it + 1]);
    int s2 = __builtin_amdgcn_readfirstlane(ssrc[it + 2]);
    int s3 = __builtin_amdgcn_readfirstlane(ssrc[it + 3]);
    int s4 = __builtin_amdgcn_readfirstlane(ssrc[it + 4]);
    int s5 = __builtin_amdgcn_readfirstlane(ssrc[it + 5]);
    int s6 = __builtin_amdgcn_readfirstlane(ssrc[it + 6]);
    int s7 = __builtin_amdgcn_readfirstlane(ssrc[it + 7]);
    float b0 = as[s0 * 8 + hd], b1 = as[s1 * 8 + hd];
    float b2 = as[s2 * 8 + hd], b3 = as[s3 * 8 + hd];
    float b4 = as[s4 * 8 + hd], b5 = as[s5 * 8 + hd];
    float b6 = as[s6 * 8 + hd], b7 = as[s7 * 8 + hd];
    union { float2 f; __half2 q[2]; } u0, u1, u2, u3, u4, u5, u6, u7;
    u0.f = *(const float2*)&h[(size_t)s0 * 256 + lane * 4];
    u1.f = *(const float2*)&h[(size_t)s1 * 256 + lane * 4];
    u2.f = *(const float2*)&h[(size_t)s2 * 256 + lane * 4];
    u3.f = *(const float2*)&h[(size_t)s3 * 256 + lane * 4];
    u4.f = *(const float2*)&h[(size_t)s4 * 256 + lane * 4];
    u5.f = *(const float2*)&h[(size_t)s5 * 256 + lane * 4];
    u6.f = *(const float2*)&h[(size_t)s6 * 256 + lane * 4];
    u7.f = *(const float2*)&h[(size_t)s7 * 256 + lane * 4];
    float p0 = __expf(lrelu(b0 + advh)), p1 = __expf(lrelu(b1 + advh));
    float p2 = __expf(lrelu(b2 + advh)), p3 = __expf(lrelu(b3 + advh));
    float p4 = __expf(lrelu(b4 + advh)), p5 = __expf(lrelu(b5 + advh));
    float p6 = __expf(lrelu(b6 + advh)), p7 = __expf(lrelu(b7 + advh));
    denom += (p0 + p1) + (p2 + p3) + ((p4 + p5) + (p6 + p7));
    __half2 ph;
    ph = __float2half2_rn(p0); acc01 = __hfma2(ph, u0.q[0], acc01); acc23 = __hfma2(ph, u0.q[1], acc23);
    ph = __float2half2_rn(p1); acc01 = __hfma2(ph, u1.q[0], acc01); acc23 = __hfma2(ph, u1.q[1], acc23);
    ph = __float2half2_rn(p2); acc01 = __hfma2(ph, u2.q[0], acc01); acc23 = __hfma2(ph, u2.q[1], acc23);
    ph = __float2half2_rn(p3); acc01 = __hfma2(ph, u3.q[0], acc01); acc23 = __hfma2(ph, u3.q[1], acc23);
    ph = __float2half2_rn(p4); acc01 = __hfma2(ph, u4.q[0], acc01); acc23 = __hfma2(ph, u4.q[1], acc23);
    ph = __float2half2_rn(p5); acc01 = __hfma2(ph, u5.q[0], acc01); acc23 = __hfma2(ph, u5.q[1], acc23);
    ph = __float2half2_rn(p6); acc01 = __hfma2(ph, u6.q[0], acc01); acc23 = __hfma2(ph, u6.q[1], acc23);
    ph = __float2half2_rn(p7); acc01 = __hfma2(ph, u7.q[0], acc01); acc23 = __hfma2(ph, u7.q[1], acc23);
  }
  for (; it < end; ++it) {
    int s = __builtin_amdgcn_readfirstlane(ssrc[it]);
    float p = __expf(lrelu(as[s * 8 + hd] + advh));
    union { float2 f; __half2 q[2]; } u;
    u.f = *(const float2*)&h[(size_t)s * 256 + lane * 4];
    __half2 ph = __float2half2_rn(p);
    acc01 = __hfma2(ph, u.q[0], acc01);
    acc23 = __hfma2(ph, u.q[1], acc23);
    denom += p;
  }
  const float inv = 1.f / (denom + 1e-16f);
  float2 a01 = __half22float2(acc01);
  float2 a23 = __half22float2(acc23);
  const float4 bv = *(const float4*)&bias[lane * 4];
  float4 o;
  o.x = a01.x * inv + bv.x; o.y = a01.y * inv + bv.y;
  o.z = a23.x * inv + bv.z; o.w = a23.y * inv + bv.w;
  o.x = o.x > 0.f ? o.x : __expf(o.x) - 1.f;
  o.y = o.y > 0.f ? o.y : __expf(o.y) - 1.f;
  o.z = o.z > 0.f ? o.z : __expf(o.z) - 1.f;
  o.w = o.w > 0.f ? o.w : __expf(o.w) - 1.f;
  union { __half2 h2[2]; float2 f2; } w;
  w.h2[0] = __floats2half2_rn(o.x, o.y);
  w.h2[1] = __floats2half2_rn(o.z, o.w);
  *(float2*)&out[(size_t)node * 256 + lane * 4] = w.f2;
}

// ---------------- layer-2 aggregation + bias + log_softmax ------------------
__global__ __launch_bounds__(256) void agg2_kernel(const __half* __restrict__ h,
    const float* __restrict__ as, const float* __restrict__ ad,
    const int* __restrict__ rs, const int* __restrict__ ssrc,
    const float* __restrict__ bias, float* __restrict__ out) {
  const int wid = (blockIdx.x * blockDim.x + threadIdx.x) >> 6;
  const int lane = threadIdx.x & 63;
  if (wid >= NN) return;
  const int node = wid;
  const int beg = rs[node], end = rs[node + 1];
  const int hd = lane >> 3;
  const float advh = ad[node * 8 + hd];
  float denom;
  __half2 acc;
  {
    float p = __expf(lrelu(as[node * 8 + hd] + advh));   // self loop
    __half2 q = ((const __half2*)&h[(size_t)node * 128])[lane];
    acc = __hmul2(__float2half2_rn(p), q);
    denom = p;
  }
  int it = beg;
  for (; it + 8 <= end; it += 8) {
    int s0 = __builtin_amdgcn_readfirstlane(ssrc[it + 0]);
    int s1 = __builtin_amdgcn_readfirstlane(ssrc[it + 1]);
    int s2 = __builtin_amdgcn_readfirstlane(ssrc[it + 2]);
    int s3 = __builtin_amdgcn_readfirstlane(ssrc[it + 3]);
    int s4 = __builtin_amdgcn_readfirstlane(ssrc[it + 4]);
    int s5 = __builtin_amdgcn_readfirstlane(ssrc[it + 5]);
    int s6 = __builtin_amdgcn_readfirstlane(ssrc[it + 6]);
    int s7 = __builtin_amdgcn_readfirstlane(ssrc[it + 7]);
    float b0 = as[s0 * 8 + hd], b1 = as[s1 * 8 + hd];
    float b2 = as[s2 * 8 + hd], b3 = as[s3 * 8 + hd];
    float b4 = as[s4 * 8 + hd], b5 = as[s5 * 8 + hd];
    float b6 = as[s6 * 8 + hd], b7 = as[s7 * 8 + hd];
    __half2 q0 = ((const __half2*)&h[(size_t)s0 * 128])[lane];
    __half2 q1 = ((const __half2*)&h[(size_t)s1 * 128])[lane];
    __half2 q2 = ((const __half2*)&h[(size_t)s2 * 128])[lane];
    __half2 q3 = ((const __half2*)&h[(size_t)s3 * 128])[lane];
    __half2 q4 = ((const __half2*)&h[(size_t)s4 * 128])[lane];
    __half2 q5 = ((const __half2*)&h[(size_t)s5 * 128])[lane];
    __half2 q6 = ((const __half2*)&h[(size_t)s6 * 128])[lane];
    __half2 q7 = ((const __half2*)&h[(size_t)s7 * 128])[lane];
    float p0 = __expf(lrelu(b0 + advh)), p1 = __expf(lrelu(b1 + advh));
    float p2 = __expf(lrelu(b2 + advh)), p3 = __expf(lrelu(b3 + advh));
    float p4 = __expf(lrelu(b4 + advh)), p5 = __expf(lrelu(b5 + advh));
    float p6 = __expf(lrelu(b6 + advh)), p7 = __expf(lrelu(b7 + advh));
    denom += (p0 + p1) + (p2 + p3) + ((p4 + p5) + (p6 + p7));
    acc = __hfma2(__float2half2_rn(p0), q0, acc);
    acc = __hfma2(__float2half2_rn(p1), q1, acc);
    acc = __hfma2(__float2half2_rn(p2), q2, acc);
    acc = __hfma2(__float2half2_rn(p3), q3, acc);
    acc = __hfma2(__float2half2_rn(p4), q4, acc);
    acc = __hfma2(__float2half2_rn(p5), q5, acc);
    acc = __hfma2(__float2half2_rn(p6), q6, acc);
    acc = __hfma2(__float2half2_rn(p7), q7, acc);
  }
  for (; it < end; ++it) {
    int s = __builtin_amdgcn_readfirstlane(ssrc[it]);
    float p = __expf(lrelu(as[s * 8 + hd] + advh));
    __half2 q = ((const __half2*)&h[(size_t)s * 128])[lane];
    acc = __hfma2(__float2half2_rn(p), q, acc);
    denom += p;
  }
  const float inv = 1.f / (denom + 1e-16f);
  float2 av = __half22float2(acc);
  float v0 = av.x * inv + bias[lane * 2 + 0];
  float v1 = av.y * inv + bias[lane * 2 + 1];
  float mx = fmaxf(v0, v1);
  #pragma unroll
  for (int off = 1; off < 64; off <<= 1) mx = fmaxf(mx, __shfl_xor(mx, off));
  float sum = __expf(v0 - mx) + __expf(v1 - mx);
  #pragma unroll
  for (int off = 1; off < 64; off <<= 1) sum += __shfl_xor(sum, off);
  float lse = mx + __logf(sum);
  float2 o = make_float2(v0 - lse, v1 - lse);
  __builtin_nontemporal_store(o.x, &out[(size_t)node * 128 + lane * 2]);
  __builtin_nontemporal_store(o.y, &out[(size_t)node * 128 + lane * 2 + 1]);
}

// ---------------- host ----------------
extern "C" void kernel_launch(void* const* d_in, const int* in_sizes, int n_in,
                              void* d_out, int out_size, void* d_ws, size_t ws_size,
                              hipStream_t stream) {
  const float* x    = (const float*)d_in[0];
  const void*  ei   = d_in[1];
  const float* W1   = (const float*)d_in[2];
  const float* aS1  = (const float*)d_in[3];
  const float* aD1  = (const float*)d_in[4];
  const float* b1   = (const float*)d_in[5];
  const float* W2   = (const float*)d_in[6];
  const float* aS2  = (const float*)d_in[7];
  const float* aD2  = (const float*)d_in[8];
  const float* b2   = (const float*)d_in[9];
  float* out = (float*)d_out;

  char* ws = (char*)d_ws;
  __half* hh   = (__half*)ws;          ws += (size_t)NN * 256 * 2;  // h (layer1) / h2 (layer2)
  __half* hmid = (__half*)ws;          ws += (size_t)NN * 256 * 2;  // ELU(agg1) fp16
  _Float16* W1t = (_Float16*)ws;       ws += (size_t)256 * 256 * 2; // [N=256][K=256]
  _Float16* W2t = (_Float16*)ws;       ws += (size_t)128 * 256 * 2; // [N=128][K=256]
  _Float16* Wa1 = (_Float16*)ws;       ws += (size_t)16 * 256 * 2;  // [16][256]
  _Float16* Wa2 = (_Float16*)ws;       ws += (size_t)16 * 256 * 2;  // [16][256]
  float* alS  = (float*)ws;            ws += (size_t)NN * 8 * 4;
  float* alD  = (float*)ws;            ws += (size_t)NN * 8 * 4;
  int* counts = (int*)ws;              ws += (size_t)NN * 4;
  int* rs     = (int*)ws;              ws += (size_t)(NN + 1) * 4;
  int* bsums  = (int*)ws;              ws += (size_t)256 * 4;
  int* ssrc   = (int*)ws;              ws += (size_t)NE * 4;
  int* flag   = (int*)ws;              ws += 256;

  const int NB = (NN + 255) / 256;     // 196 scan blocks

  // ---- CSR build ----
  detect_i64_kernel<<<1, 64, 0, stream>>>((const unsigned*)ei, flag);
  hipMemsetAsync(counts, 0, (size_t)NN * 4, stream);
  count_kernel<<<(NE + 255) / 256, 256, 0, stream>>>(ei, flag, counts);
  scan1_kernel<<<NB, 256, 0, stream>>>(counts, bsums);
  scan2_kernel<<<1, 256, 0, stream>>>(bsums, NB);
  scan3_kernel<<<NB, 256, 0, stream>>>(counts, bsums, rs);
  hipMemsetAsync(counts, 0, (size_t)NN * 4, stream);
  scatter_kernel<<<(NE + 255) / 256, 256, 0, stream>>>(ei, flag, rs, counts, ssrc);

  // ---- weight prep ----
  convert_wt_kernel<<<(256 * 256 + 255) / 256, 256, 0, stream>>>(W1, W1t, 256, 256 * 256);
  convert_wt_kernel<<<(128 * 256 + 255) / 256, 256, 0, stream>>>(W2, W2t, 128, 128 * 256);
  convert_wa_kernel<<<16, 256, 0, stream>>>(W1, aS1, aD1, Wa1, 256, 32);
  convert_wa_kernel<<<16, 256, 0, stream>>>(W2, aS2, aD2, Wa2, 128, 16);

  const int ngrid = (NN + 63) / 64;  // 782
  // ---- layer 1 ----
  gemm_mfma<256, 4, false><<<ngrid, 256, 0, stream>>>(x, W1t, Wa1, hh, alS, alD, NN);
  agg1_kernel<<<(NN + 3) / 4, 256, 0, stream>>>(hh, alS, alD, rs, ssrc, b1, hmid);

  // ---- layer 2 ----
  gemm_mfma<128, 2, true><<<ngrid, 256, 0, stream>>>(hmid, W2t, Wa2, hh, alS, alD, NN);
  agg2_kernel<<<(NN + 3) / 4, 256, 0, stream>>>(hh, alS, alD, rs, ssrc, b2, out);
}

// Round 9
// 265.498 us; speedup vs baseline: 1.2936x; 1.0484x over previous
//
#include <hip/hip_runtime.h>
#include <hip/hip_fp16.h>

#define NN 50000
#define NE 800000

typedef _Float16 half4v __attribute__((ext_vector_type(4)));
typedef _Float16 half8v __attribute__((ext_vector_type(8)));
typedef float f32x4 __attribute__((ext_vector_type(4)));

static __device__ __forceinline__ float lrelu(float x) { return x > 0.f ? x : 0.2f * x; }

// ---------------- edge-index dtype detection (int32 vs int64) ----------------
__global__ void detect_i64_kernel(const unsigned* __restrict__ ei, int* __restrict__ flag) {
  if (threadIdx.x == 0 && blockIdx.x == 0) {
    int is64 = 1;
    for (int i = 0; i < 64; ++i)
      if (ei[2 * i + 1] != 0u) { is64 = 0; break; }
    *flag = is64;
  }
}

static __device__ __forceinline__ int edge_at(const void* ei, int is64, long long idx) {
  if (is64) return (int)((const long long*)ei)[idx];
  return ((const int*)ei)[idx];
}

// ---------------- CSR build ----------------
__global__ void count_kernel(const void* __restrict__ ei, const int* __restrict__ flag,
                             int* __restrict__ counts) {
  int e = blockIdx.x * blockDim.x + threadIdx.x;
  if (e >= NE) return;
  int is64 = *flag;
  int d = edge_at(ei, is64, (long long)NE + e);
  atomicAdd(&counts[d], 1);
}

// two-level scan: 196 blocks x 256
static __device__ __forceinline__ int block_scan_inc(int v, int tid) {
  __shared__ int ws[4];
  const int lane = tid & 63, wv = tid >> 6;
  #pragma unroll
  for (int off = 1; off < 64; off <<= 1) {
    int t = __shfl_up(v, off);
    if (lane >= off) v += t;
  }
  if (lane == 63) ws[wv] = v;
  __syncthreads();
  int add = 0;
  #pragma unroll
  for (int j = 0; j < 4; ++j) if (j < wv) add += ws[j];
  return v + add;
}

__global__ void scan1_kernel(const int* __restrict__ counts, int* __restrict__ bsums) {
  __shared__ int ws[4];
  const int tid = threadIdx.x;
  const int lane = tid & 63, wv = tid >> 6;
  int i = blockIdx.x * 256 + tid;
  int v = (i < NN) ? counts[i] : 0;
  #pragma unroll
  for (int off = 1; off < 64; off <<= 1) v += __shfl_xor(v, off);
  if (lane == 0) ws[wv] = v;
  __syncthreads();
  if (tid == 0) bsums[blockIdx.x] = ws[0] + ws[1] + ws[2] + ws[3];
}

__global__ void scan2_kernel(int* __restrict__ bsums, int nb) {
  const int tid = threadIdx.x;
  int v = (tid < nb) ? bsums[tid] : 0;
  int inc = block_scan_inc(v, tid);
  if (tid < nb) bsums[tid] = inc - v;   // exclusive
}

__global__ void scan3_kernel(const int* __restrict__ counts, const int* __restrict__ bsums,
                             int* __restrict__ rs) {
  const int tid = threadIdx.x;
  int i = blockIdx.x * 256 + tid;
  int v = (i < NN) ? counts[i] : 0;
  int inc = block_scan_inc(v, tid);
  if (i < NN) rs[i + 1] = bsums[blockIdx.x] + inc;
  if (i == 0) rs[0] = 0;
}

__global__ void scatter_kernel(const void* __restrict__ ei, const int* __restrict__ flag,
                               const int* __restrict__ rs, int* __restrict__ cursor,
                               int* __restrict__ ssrc) {
  int e = blockIdx.x * blockDim.x + threadIdx.x;
  if (e >= NE) return;
  int is64 = *flag;
  int s = edge_at(ei, is64, e);
  int d = edge_at(ei, is64, (long long)NE + e);
  int p = atomicAdd(&cursor[d], 1);
  ssrc[rs[d] + p] = s;
}

// ---------------- fused weight prep: W1t, W2t, Wa1, Wa2 ----------------------
// ranges: [0,65536) W1t ; [65536,98304) W2t ; [98304,102400) Wa1 ; [102400,106496) Wa2
__global__ void prep_kernel(const float* __restrict__ W1, const float* __restrict__ W2,
                            const float* __restrict__ aS1, const float* __restrict__ aD1,
                            const float* __restrict__ aS2, const float* __restrict__ aD2,
                            _Float16* __restrict__ W1t, _Float16* __restrict__ W2t,
                            _Float16* __restrict__ Wa1, _Float16* __restrict__ Wa2) {
  int i = blockIdx.x * blockDim.x + threadIdx.x;
  if (i < 65536) {
    int n = i >> 8, k = i & 255;
    W1t[i] = (_Float16)W1[(size_t)k * 256 + n];
  } else if (i < 98304) {
    int j = i - 65536;
    int n = j >> 8, k = j & 255;
    W2t[j] = (_Float16)W2[(size_t)k * 128 + n];
  } else if (i < 102400) {
    int j = i - 98304;
    int row = j >> 8, k = j & 255;     // row 0..15
    int head = row & 7;
    const float* a = (row < 8) ? aS1 : aD1;
    float s = 0.f;
    #pragma unroll 8
    for (int c = 0; c < 32; ++c)
      s += W1[(size_t)k * 256 + head * 32 + c] * a[head * 32 + c];
    Wa1[j] = (_Float16)s;
  } else if (i < 106496) {
    int j = i - 102400;
    int row = j >> 8, k = j & 255;
    int head = row & 7;
    const float* a = (row < 8) ? aS2 : aD2;
    float s = 0.f;
    #pragma unroll 8
    for (int c = 0; c < 16; ++c)
      s += W2[(size_t)k * 128 + head * 16 + c] * a[head * 16 + c];
    Wa2[j] = (_Float16)s;
  }
}

// ---------------- MFMA fp16 GEMM + fused alpha columns -----------------------
template<int BN, int NCF, bool A_HALF>
__global__ __launch_bounds__(256) void gemm_mfma(const void* __restrict__ Araw,
                                                 const _Float16* __restrict__ Wt,
                                                 const _Float16* __restrict__ Wa,
                                                 __half* __restrict__ C,
                                                 float* __restrict__ alS,
                                                 float* __restrict__ alD, int M) {
  __shared__ _Float16 As[64][256 + 8];
  const int tid = threadIdx.x;
  const int bm0 = blockIdx.x * 64;
  if (A_HALF) {
    const _Float16* A = (const _Float16*)Araw;
    for (int idx = tid; idx < 64 * 32; idx += 256) {
      int r = idx >> 5, c8 = (idx & 31) << 3;
      int gr = bm0 + r;
      half8v v = {};
      if (gr < M) v = *(const half8v*)&A[(size_t)gr * 256 + c8];
      *(half8v*)&As[r][c8] = v;
    }
  } else {
    const float* A = (const float*)Araw;
    for (int idx = tid; idx < 64 * 64; idx += 256) {
      int r = idx >> 6, c4 = (idx & 63) << 2;
      int gr = bm0 + r;
      float4 v = make_float4(0.f, 0.f, 0.f, 0.f);
      if (gr < M) v = *(const float4*)&A[(size_t)gr * 256 + c4];
      half4v h = { (_Float16)v.x, (_Float16)v.y, (_Float16)v.z, (_Float16)v.w };
      *(half4v*)&As[r][c4] = h;
    }
  }
  __syncthreads();
  const int lane = tid & 63, wv = tid >> 6;
  const int ncol0 = wv * (16 * NCF);
  const int lrow = lane & 15, lk8 = (lane >> 4) << 3;
  f32x4 acc[4][NCF];
  f32x4 acca[4];
  #pragma unroll
  for (int rf = 0; rf < 4; ++rf) {
    acca[rf] = (f32x4){0.f, 0.f, 0.f, 0.f};
    #pragma unroll
    for (int cf = 0; cf < NCF; ++cf) acc[rf][cf] = (f32x4){0.f, 0.f, 0.f, 0.f};
  }
  #pragma unroll
  for (int k0 = 0; k0 < 256; k0 += 32) {
    const int ks = k0 + lk8;
    half8v af[4];
    #pragma unroll
    for (int rf = 0; rf < 4; ++rf)
      af[rf] = *(const half8v*)&As[16 * rf + lrow][ks];
    #pragma unroll
    for (int cf = 0; cf < NCF; ++cf) {
      half8v bf = *(const half8v*)&Wt[(size_t)(ncol0 + 16 * cf + lrow) * 256 + ks];
      #pragma unroll
      for (int rf = 0; rf < 4; ++rf)
        acc[rf][cf] = __builtin_amdgcn_mfma_f32_16x16x32_f16(af[rf], bf, acc[rf][cf], 0, 0, 0);
    }
    if (wv == 0) {
      half8v bfa = *(const half8v*)&Wa[(size_t)lrow * 256 + ks];
      #pragma unroll
      for (int rf = 0; rf < 4; ++rf)
        acca[rf] = __builtin_amdgcn_mfma_f32_16x16x32_f16(af[rf], bfa, acca[rf], 0, 0, 0);
    }
  }
  #pragma unroll
  for (int rf = 0; rf < 4; ++rf) {
    #pragma unroll
    for (int j = 0; j < 4; ++j) {
      int row = bm0 + 16 * rf + 4 * (lane >> 4) + j;
      if (row < M) {
        #pragma unroll
        for (int cf = 0; cf < NCF; ++cf) {
          int col = ncol0 + 16 * cf + lrow;
          C[(size_t)row * BN + col] = __float2half(acc[rf][cf][j]);
        }
      }
    }
  }
  if (wv == 0) {
    #pragma unroll
    for (int rf = 0; rf < 4; ++rf) {
      #pragma unroll
      for (int j = 0; j < 4; ++j) {
        int row = bm0 + 16 * rf + 4 * (lane >> 4) + j;
        if (row < M) {
          float v = acca[rf][j];
          if (lrow < 8) alS[row * 8 + lrow] = v;
          else          alD[row * 8 + (lrow - 8)] = v;
        }
      }
    }
  }
}

// ---------------- layer-1 aggregation: readlane-broadcast gather-FMA --------
// one wave per node; edge srcs vector-loaded once, broadcast via readlane ->
// gather addresses have no memory dependency; fp16 accumulate.
__global__ __launch_bounds__(256) void agg1_kernel(const __half* __restrict__ h,
    const float* __restrict__ as, const float* __restrict__ ad,
    const int* __restrict__ rs, const int* __restrict__ ssrc,
    const float* __restrict__ bias, __half* __restrict__ out) {
  const int wid = (blockIdx.x * blockDim.x + threadIdx.x) >> 6;
  const int lane = threadIdx.x & 63;
  if (wid >= NN) return;
  const int node = wid;
  const int beg = rs[node], end = rs[node + 1];
  const int deg = end - beg;
  const int hd = lane >> 3;
  const float advh = ad[node * 8 + hd];
  float denom;
  __half2 acc01, acc23;
  {
    float p = __expf(lrelu(as[node * 8 + hd] + advh));   // self loop
    union { float2 f; __half2 q[2]; } u;
    u.f = *(const float2*)&h[(size_t)node * 256 + lane * 4];
    __half2 p2 = __float2half2_rn(p);
    acc01 = __hmul2(p2, u.q[0]);
    acc23 = __hmul2(p2, u.q[1]);
    denom = p;
  }
  for (int base = 0; base < deg; base += 64) {
    const int cnt = min(deg - base, 64);
    int sv = (lane < cnt) ? ssrc[beg + base + lane] : 0;  // one coalesced load
    int j = 0;
    for (; j + 8 <= cnt; j += 8) {
      int s0 = __builtin_amdgcn_readlane(sv, j + 0);
      int s1 = __builtin_amdgcn_readlane(sv, j + 1);
      int s2 = __builtin_amdgcn_readlane(sv, j + 2);
      int s3 = __builtin_amdgcn_readlane(sv, j + 3);
      int s4 = __builtin_amdgcn_readlane(sv, j + 4);
      int s5 = __builtin_amdgcn_readlane(sv, j + 5);
      int s6 = __builtin_amdgcn_readlane(sv, j + 6);
      int s7 = __builtin_amdgcn_readlane(sv, j + 7);
      float b0 = as[s0 * 8 + hd], b1 = as[s1 * 8 + hd];
      float b2 = as[s2 * 8 + hd], b3 = as[s3 * 8 + hd];
      float b4 = as[s4 * 8 + hd], b5 = as[s5 * 8 + hd];
      float b6 = as[s6 * 8 + hd], b7 = as[s7 * 8 + hd];
      union { float2 f; __half2 q[2]; } u0, u1, u2, u3, u4, u5, u6, u7;
      u0.f = *(const float2*)&h[(size_t)s0 * 256 + lane * 4];
      u1.f = *(const float2*)&h[(size_t)s1 * 256 + lane * 4];
      u2.f = *(const float2*)&h[(size_t)s2 * 256 + lane * 4];
      u3.f = *(const float2*)&h[(size_t)s3 * 256 + lane * 4];
      u4.f = *(const float2*)&h[(size_t)s4 * 256 + lane * 4];
      u5.f = *(const float2*)&h[(size_t)s5 * 256 + lane * 4];
      u6.f = *(const float2*)&h[(size_t)s6 * 256 + lane * 4];
      u7.f = *(const float2*)&h[(size_t)s7 * 256 + lane * 4];
      float p0 = __expf(lrelu(b0 + advh)), p1 = __expf(lrelu(b1 + advh));
      float p2 = __expf(lrelu(b2 + advh)), p3 = __expf(lrelu(b3 + advh));
      float p4 = __expf(lrelu(b4 + advh)), p5 = __expf(lrelu(b5 + advh));
      float p6 = __expf(lrelu(b6 + advh)), p7 = __expf(lrelu(b7 + advh));
      denom += (p0 + p1) + (p2 + p3) + ((p4 + p5) + (p6 + p7));
      __half2 ph;
      ph = __float2half2_rn(p0); acc01 = __hfma2(ph, u0.q[0], acc01); acc23 = __hfma2(ph, u0.q[1], acc23);
      ph = __float2half2_rn(p1); acc01 = __hfma2(ph, u1.q[0], acc01); acc23 = __hfma2(ph, u1.q[1], acc23);
      ph = __float2half2_rn(p2); acc01 = __hfma2(ph, u2.q[0], acc01); acc23 = __hfma2(ph, u2.q[1], acc23);
      ph = __float2half2_rn(p3); acc01 = __hfma2(ph, u3.q[0], acc01); acc23 = __hfma2(ph, u3.q[1], acc23);
      ph = __float2half2_rn(p4); acc01 = __hfma2(ph, u4.q[0], acc01); acc23 = __hfma2(ph, u4.q[1], acc23);
      ph = __float2half2_rn(p5); acc01 = __hfma2(ph, u5.q[0], acc01); acc23 = __hfma2(ph, u5.q[1], acc23);
      ph = __float2half2_rn(p6); acc01 = __hfma2(ph, u6.q[0], acc01); acc23 = __hfma2(ph, u6.q[1], acc23);
      ph = __float2half2_rn(p7); acc01 = __hfma2(ph, u7.q[0], acc01); acc23 = __hfma2(ph, u7.q[1], acc23);
    }
    for (; j < cnt; ++j) {
      int s = __builtin_amdgcn_readlane(sv, j);
      float p = __expf(lrelu(as[s * 8 + hd] + advh));
      union { float2 f; __half2 q[2]; } u;
      u.f = *(const float2*)&h[(size_t)s * 256 + lane * 4];
      __half2 ph = __float2half2_rn(p);
      acc01 = __hfma2(ph, u.q[0], acc01);
      acc23 = __hfma2(ph, u.q[1], acc23);
      denom += p;
    }
  }
  const float inv = 1.f / (denom + 1e-16f);
  float2 a01 = __half22float2(acc01);
  float2 a23 = __half22float2(acc23);
  const float4 bv = *(const float4*)&bias[lane * 4];
  float4 o;
  o.x = a01.x * inv + bv.x; o.y = a01.y * inv + bv.y;
  o.z = a23.x * inv + bv.z; o.w = a23.y * inv + bv.w;
  o.x = o.x > 0.f ? o.x : __expf(o.x) - 1.f;
  o.y = o.y > 0.f ? o.y : __expf(o.y) - 1.f;
  o.z = o.z > 0.f ? o.z : __expf(o.z) - 1.f;
  o.w = o.w > 0.f ? o.w : __expf(o.w) - 1.f;
  union { __half2 h2[2]; float2 f2; } w;
  w.h2[0] = __floats2half2_rn(o.x, o.y);
  w.h2[1] = __floats2half2_rn(o.z, o.w);
  *(float2*)&out[(size_t)node * 256 + lane * 4] = w.f2;
}

// ---------------- layer-2 aggregation + bias + log_softmax ------------------
__global__ __launch_bounds__(256) void agg2_kernel(const __half* __restrict__ h,
    const float* __restrict__ as, const float* __restrict__ ad,
    const int* __restrict__ rs, const int* __restrict__ ssrc,
    const float* __restrict__ bias, float* __restrict__ out) {
  const int wid = (blockIdx.x * blockDim.x + threadIdx.x) >> 6;
  const int lane = threadIdx.x & 63;
  if (wid >= NN) return;
  const int node = wid;
  const int beg = rs[node], end = rs[node + 1];
  const int deg = end - beg;
  const int hd = lane >> 3;
  const float advh = ad[node * 8 + hd];
  float denom;
  __half2 acc;
  {
    float p = __expf(lrelu(as[node * 8 + hd] + advh));   // self loop
    __half2 q = ((const __half2*)&h[(size_t)node * 128])[lane];
    acc = __hmul2(__float2half2_rn(p), q);
    denom = p;
  }
  for (int base = 0; base < deg; base += 64) {
    const int cnt = min(deg - base, 64);
    int sv = (lane < cnt) ? ssrc[beg + base + lane] : 0;
    int j = 0;
    for (; j + 8 <= cnt; j += 8) {
      int s0 = __builtin_amdgcn_readlane(sv, j + 0);
      int s1 = __builtin_amdgcn_readlane(sv, j + 1);
      int s2 = __builtin_amdgcn_readlane(sv, j + 2);
      int s3 = __builtin_amdgcn_readlane(sv, j + 3);
      int s4 = __builtin_amdgcn_readlane(sv, j + 4);
      int s5 = __builtin_amdgcn_readlane(sv, j + 5);
      int s6 = __builtin_amdgcn_readlane(sv, j + 6);
      int s7 = __builtin_amdgcn_readlane(sv, j + 7);
      float b0 = as[s0 * 8 + hd], b1 = as[s1 * 8 + hd];
      float b2 = as[s2 * 8 + hd], b3 = as[s3 * 8 + hd];
      float b4 = as[s4 * 8 + hd], b5 = as[s5 * 8 + hd];
      float b6 = as[s6 * 8 + hd], b7 = as[s7 * 8 + hd];
      __half2 q0 = ((const __half2*)&h[(size_t)s0 * 128])[lane];
      __half2 q1 = ((const __half2*)&h[(size_t)s1 * 128])[lane];
      __half2 q2 = ((const __half2*)&h[(size_t)s2 * 128])[lane];
      __half2 q3 = ((const __half2*)&h[(size_t)s3 * 128])[lane];
      __half2 q4 = ((const __half2*)&h[(size_t)s4 * 128])[lane];
      __half2 q5 = ((const __half2*)&h[(size_t)s5 * 128])[lane];
      __half2 q6 = ((const __half2*)&h[(size_t)s6 * 128])[lane];
      __half2 q7 = ((const __half2*)&h[(size_t)s7 * 128])[lane];
      float p0 = __expf(lrelu(b0 + advh)), p1 = __expf(lrelu(b1 + advh));
      float p2 = __expf(lrelu(b2 + advh)), p3 = __expf(lrelu(b3 + advh));
      float p4 = __expf(lrelu(b4 + advh)), p5 = __expf(lrelu(b5 + advh));
      float p6 = __expf(lrelu(b6 + advh)), p7 = __expf(lrelu(b7 + advh));
      denom += (p0 + p1) + (p2 + p3) + ((p4 + p5) + (p6 + p7));
      acc = __hfma2(__float2half2_rn(p0), q0, acc);
      acc = __hfma2(__float2half2_rn(p1), q1, acc);
      acc = __hfma2(__float2half2_rn(p2), q2, acc);
      acc = __hfma2(__float2half2_rn(p3), q3, acc);
      acc = __hfma2(__float2half2_rn(p4), q4, acc);
      acc = __hfma2(__float2half2_rn(p5), q5, acc);
      acc = __hfma2(__float2half2_rn(p6), q6, acc);
      acc = __hfma2(__float2half2_rn(p7), q7, acc);
    }
    for (; j < cnt; ++j) {
      int s = __builtin_amdgcn_readlane(sv, j);
      float p = __expf(lrelu(as[s * 8 + hd] + advh));
      __half2 q = ((const __half2*)&h[(size_t)s * 128])[lane];
      acc = __hfma2(__float2half2_rn(p), q, acc);
      denom += p;
    }
  }
  const float inv = 1.f / (denom + 1e-16f);
  float2 av = __half22float2(acc);
  float v0 = av.x * inv + bias[lane * 2 + 0];
  float v1 = av.y * inv + bias[lane * 2 + 1];
  float mx = fmaxf(v0, v1);
  #pragma unroll
  for (int off = 1; off < 64; off <<= 1) mx = fmaxf(mx, __shfl_xor(mx, off));
  float sum = __expf(v0 - mx) + __expf(v1 - mx);
  #pragma unroll
  for (int off = 1; off < 64; off <<= 1) sum += __shfl_xor(sum, off);
  float lse = mx + __logf(sum);
  float2 o = make_float2(v0 - lse, v1 - lse);
  __builtin_nontemporal_store(o.x, &out[(size_t)node * 128 + lane * 2]);
  __builtin_nontemporal_store(o.y, &out[(size_t)node * 128 + lane * 2 + 1]);
}

// ---------------- host ----------------
extern "C" void kernel_launch(void* const* d_in, const int* in_sizes, int n_in,
                              void* d_out, int out_size, void* d_ws, size_t ws_size,
                              hipStream_t stream) {
  const float* x    = (const float*)d_in[0];
  const void*  ei   = d_in[1];
  const float* W1   = (const float*)d_in[2];
  const float* aS1  = (const float*)d_in[3];
  const float* aD1  = (const float*)d_in[4];
  const float* b1   = (const float*)d_in[5];
  const float* W2   = (const float*)d_in[6];
  const float* aS2  = (const float*)d_in[7];
  const float* aD2  = (const float*)d_in[8];
  const float* b2   = (const float*)d_in[9];
  float* out = (float*)d_out;

  char* ws = (char*)d_ws;
  __half* hh   = (__half*)ws;          ws += (size_t)NN * 256 * 2;  // h (layer1) / h2 (layer2)
  __half* hmid = (__half*)ws;          ws += (size_t)NN * 256 * 2;  // ELU(agg1) fp16
  _Float16* W1t = (_Float16*)ws;       ws += (size_t)256 * 256 * 2; // [N=256][K=256]
  _Float16* W2t = (_Float16*)ws;       ws += (size_t)128 * 256 * 2; // [N=128][K=256]
  _Float16* Wa1 = (_Float16*)ws;       ws += (size_t)16 * 256 * 2;  // [16][256]
  _Float16* Wa2 = (_Float16*)ws;       ws += (size_t)16 * 256 * 2;  // [16][256]
  float* alS  = (float*)ws;            ws += (size_t)NN * 8 * 4;
  float* alD  = (float*)ws;            ws += (size_t)NN * 8 * 4;
  int* counts = (int*)ws;              ws += (size_t)NN * 4;
  int* rs     = (int*)ws;              ws += (size_t)(NN + 1) * 4;
  int* bsums  = (int*)ws;              ws += (size_t)256 * 4;
  int* ssrc   = (int*)ws;              ws += (size_t)NE * 4;
  int* flag   = (int*)ws;              ws += 256;

  const int NB = (NN + 255) / 256;     // 196 scan blocks

  // ---- CSR build ----
  detect_i64_kernel<<<1, 64, 0, stream>>>((const unsigned*)ei, flag);
  hipMemsetAsync(counts, 0, (size_t)NN * 4, stream);
  count_kernel<<<(NE + 255) / 256, 256, 0, stream>>>(ei, flag, counts);
  scan1_kernel<<<NB, 256, 0, stream>>>(counts, bsums);
  scan2_kernel<<<1, 256, 0, stream>>>(bsums, NB);
  scan3_kernel<<<NB, 256, 0, stream>>>(counts, bsums, rs);
  hipMemsetAsync(counts, 0, (size_t)NN * 4, stream);
  scatter_kernel<<<(NE + 255) / 256, 256, 0, stream>>>(ei, flag, rs, counts, ssrc);

  // ---- weight prep (fused) ----
  prep_kernel<<<(106496 + 255) / 256, 256, 0, stream>>>(W1, W2, aS1, aD1, aS2, aD2,
                                                        W1t, W2t, Wa1, Wa2);

  const int ngrid = (NN + 63) / 64;  // 782
  // ---- layer 1 ----
  gemm_mfma<256, 4, false><<<ngrid, 256, 0, stream>>>(x, W1t, Wa1, hh, alS, alD, NN);
  agg1_kernel<<<(NN + 3) / 4, 256, 0, stream>>>(hh, alS, alD, rs, ssrc, b1, hmid);

  // ---- layer 2 ----
  gemm_mfma<128, 2, true><<<ngrid, 256, 0, stream>>>(hmid, W2t, Wa2, hh, alS, alD, NN);
  agg2_kernel<<<(NN + 3) / 4, 256, 0, stream>>>(hh, alS, alD, rs, ssrc, b2, out);
}